// Round 15
// baseline (122.658 us; speedup 1.0000x reference)
//
#include <hip/hip_runtime.h>
#include <math.h>

#define PMAX 22
#define HID 64
#define OUTD 128
#define SETS_PER_WAVE 8
#define WAVES_PER_BLOCK 4
#define ROWS 176      // 8 sets * 22 player-rows per wave
#define ROWS_PAD 192  // padded to 6 k-tiles of 32 for the pooling MFMA

typedef __attribute__((ext_vector_type(4))) float float4v;
typedef _Float16 half8 __attribute__((ext_vector_type(8)));

union U4 { uint4 u4; half8 h8; unsigned u[4]; };

__device__ __forceinline__ unsigned pk2(float x, float y) {
    auto v = __builtin_amdgcn_cvt_pkrtz(x, y);
    union { decltype(v) h; unsigned i; } c;
    c.h = v;
    return c.i;
}
__device__ __forceinline__ unsigned short f16b(float x) {
    return (unsigned short)(pk2(x, x) & 0xFFFF);
}
__device__ __forceinline__ void wave_lds_sync() {
    asm volatile("s_waitcnt lgkmcnt(0)" ::: "memory");
    __builtin_amdgcn_wave_barrier();
}
__device__ __forceinline__ float fast_atan2(float y, float x) {
    float ax = fabsf(x), ay = fabsf(y);
    float mn = fminf(ax, ay), mx = fmaxf(ax, ay);
    float a = mn * __builtin_amdgcn_rcpf(fmaxf(mx, 1e-30f));
    float s = a * a;
    float r = a * fmaf(s, fmaf(s, fmaf(s, -0.0851330f, 0.1801410f), -0.3302995f), 0.9998660f);
    if (ay > ax) r = 1.57079637f - r;
    if (x < 0.0f) r = 3.14159274f - r;
    return copysignf(r, y);
}

__global__ __launch_bounds__(256) void set_encoder_kernel(
    const float* __restrict__ player_locs,  // [B,22,2]
    const float* __restrict__ actor_locs,   // [B,2]
    const float* __restrict__ flags,        // [B,22,2]
    const int*   __restrict__ mask,         // [B,22]
    const float* __restrict__ W1,           // [6,64]
    const float* __restrict__ b1,           // [64]
    const float* __restrict__ W2,           // [64,128]
    const float* __restrict__ b2,           // [128]
    float* __restrict__ out)                // [B,128]
{
    __shared__ __align__(16) unsigned w2f[16 * 256];                         // 16 KB
    __shared__ __align__(16) unsigned feats[WAVES_PER_BLOCK * ROWS_PAD * 4]; // 12 KB
    __shared__ __align__(16) unsigned Hl[WAVES_PER_BLOCK * 64 * 20];         // 20 KB
    __shared__ __align__(16) unsigned short hb[WAVES_PER_BLOCK][SETS_PER_WAVE][72];

    const int tid  = threadIdx.x;
    const int lane = tid & 63;
    const int wave = tid >> 6;
    const int Q    = lane >> 4;
    const int c15  = lane & 15;

    const int wave_id = blockIdx.x * WAVES_PER_BLOCK + wave;
    const int set0    = wave_id * SETS_PER_WAVE;

    unsigned* featw = &feats[wave * ROWS_PAD * 4];
    unsigned* Hw    = &Hl[wave * 64 * 20];

    // --- W2 -> LDS B-fragments, f16 (block-cooperative, one-time) ---
    {
        const int pr = tid >> 3;
        const int nt = tid & 7;
        const float* rA = W2 + (size_t)(2 * pr) * OUTD + 16 * nt;
        const float* rB = rA + OUTD;
        float ra[16], rb[16];
#pragma unroll
        for (int i = 0; i < 4; ++i) {
            *(float4*)&ra[4 * i] = ((const float4*)rA)[i];
            *(float4*)&rb[4 * i] = ((const float4*)rB)[i];
        }
        const int kt = pr >> 4;
        const int kk = (2 * pr) & 31;
        const int q  = kk >> 3;
        const int j2 = (kk >> 1) & 3;
        const int base = ((kt * 8 + nt) * 4 + q) * 64 + j2;
#pragma unroll
        for (int c = 0; c < 16; ++c)
            w2f[base + 4 * c] = pk2(ra[c], rb[c]);
    }

    // --- W1 B-frags in regs: B[k=8Q+j][n=16nt+c15]; k=6 row carries b1
    //     (paired with a constant-1 feature), k=7 and quads 1-3 zero. ---
    U4 w1f[4];
#pragma unroll
    for (int nt = 0; nt < 4; ++nt) {
        const int col = 16 * nt + c15;
        const bool q0 = (Q == 0);
        float a0 = W1[0 * HID + col], a1 = W1[1 * HID + col];
        float a2 = W1[2 * HID + col], a3 = W1[3 * HID + col];
        float a4 = W1[4 * HID + col], a5 = W1[5 * HID + col];
        float bb = b1[col];
        w1f[nt].u[0] = q0 ? pk2(a0, a1) : 0u;
        w1f[nt].u[1] = q0 ? pk2(a2, a3) : 0u;
        w1f[nt].u[2] = q0 ? pk2(a4, a5) : 0u;
        w1f[nt].u[3] = q0 ? pk2(bb, 0.f) : 0u;   // k=6 -> b1, k=7 -> 0
    }

    __syncthreads();  // w2f visible (only block barrier)

    // --- phase 0: features -> feats LDS (A-frag k-order); ballots ---
    unsigned long long wbm[4];
    {
        const int lidx = lane < 2 * PMAX ? lane : 2 * PMAX - 1;  // clamp
        const size_t r0 = (size_t)set0 * PMAX + lidx;
        const float2* plb = (const float2*)player_locs + r0;
        const float2* flb = (const float2*)flags + r0;
        const int*    mkb = mask + r0;
        const float2* acb = (const float2*)actor_locs + set0 + (lidx >= PMAX ? 1 : 0);
#pragma unroll
        for (int g = 0; g < 4; ++g) {
            float2 pl = plb[g * 2 * PMAX];
            float2 fl = flb[g * 2 * PMAX];
            int    m  = mkb[g * 2 * PMAX];
            float2 ac = acb[2 * g];
            float dx = pl.x - ac.x;
            float dy = pl.y - ac.y;
            float dist = __builtin_amdgcn_sqrtf(fmaf(dx, dx, dy * dy));
            float ang  = fast_atan2(dy, dx);
            if (lane < 2 * PMAX) {
                uint4 v;
                v.x = pk2(dx, dy);
                v.y = pk2(dist, ang);
                v.z = pk2(fl.x, fl.y);
                v.w = pk2(1.0f, 0.f);   // k=6 constant 1 pairs with b1 row
                *(uint4*)&featw[(g * 44 + lane) * 4] = v;
            }
            unsigned long long bl = __ballot((lane < 2 * PMAX) && (m != 0));
            const unsigned lo = __builtin_amdgcn_readfirstlane((unsigned)bl);
            const unsigned hi = __builtin_amdgcn_readfirstlane((unsigned)(bl >> 32));
            wbm[g] = ((unsigned long long)hi << 32) | lo;  // uniform
        }
    }
    if (lane < 16) {  // zero pad rows 176..191 (pad rows: h=relu(0)=0, M=0)
        uint4 z = {0u, 0u, 0u, 0u};
        *(uint4*)&featw[(ROWS + lane) * 4] = z;
    }
    wave_lds_sync();

    // --- uniform 176-bit validity bitmap as 6 dwords + per-set counts ---
    unsigned bm32[6];
    {
        unsigned long long t0 = wbm[0] | (wbm[1] << 44);
        unsigned long long t1 = (wbm[1] >> 20) | (wbm[2] << 24);
        unsigned long long t2 = (wbm[2] >> 40) | (wbm[3] << 4);
        bm32[0] = (unsigned)t0; bm32[1] = (unsigned)(t0 >> 32);
        bm32[2] = (unsigned)t1; bm32[3] = (unsigned)(t1 >> 32);
        bm32[4] = (unsigned)t2; bm32[5] = (unsigned)(t2 >> 32);
    }
    unsigned nonempty = 0;
    float rcpc[8];
#pragma unroll
    for (int s = 0; s < 8; ++s) {
        unsigned bits = (unsigned)(wbm[s >> 1] >> ((s & 1) * PMAX)) & 0x3FFFFFu;
        int cnt = __builtin_popcount(bits);
        if (bits) nonempty |= (1u << s);
        rcpc[s] = 1.0f / (float)(cnt > 0 ? cnt : 1);
    }

    float4v pacc[4];
#pragma unroll
    for (int nt = 0; nt < 4; ++nt) pacc[nt] = (float4v){0.f, 0.f, 0.f, 0.f};

    const int vd0 = 8 * Q - PMAX * c15;

#pragma unroll
    for (int kt = 0; kt < 6; ++kt) {
#pragma unroll
        for (int i = 0; i < 2; ++i) {
            const int tt = 2 * kt + i;
            const int arow = (Q == 0) ? (16 * tt + c15) : (ROWS + c15);
            U4 av;
            av.u4 = *(const uint4*)&featw[arow * 4];
#pragma unroll
            for (int nt = 0; nt < 4; ++nt) {
                float4v z = {0.f, 0.f, 0.f, 0.f};
                float4v c1 = __builtin_amdgcn_mfma_f32_16x16x32_f16(av.h8, w1f[nt].h8, z, 0, 0, 0);
                uint2 wv;
                wv.x = pk2(fmaxf(c1[0], 0.f), fmaxf(c1[1], 0.f));
                wv.y = pk2(fmaxf(c1[2], 0.f), fmaxf(c1[3], 0.f));
                *(uint2*)&Hw[(16 * nt + c15) * 20 + 8 * i + 2 * Q] = wv;
            }
        }
        wave_lds_sync();

        unsigned bits8 = (bm32[kt] >> (8 * Q)) & 0xFFu;
        const int d = vd0 + 32 * kt;
        unsigned rp = 0x3FFFFFu >> (d & 31);
        unsigned rn = 0x3FFFFFu << ((-d) & 31);
        unsigned rm = (d >= 0) ? rp : rn;
        rm = (d >= 22) ? 0u : rm;
        rm = (d <= -8) ? 0u : rm;
        unsigned m8 = bits8 & rm;
        U4 mf;
#pragma unroll
        for (int j2 = 0; j2 < 4; ++j2) {
            unsigned b = (m8 >> (2 * j2)) & 3u;
            mf.u[j2] = ((b & 1u) ? 0x00003C00u : 0u) | ((b & 2u) ? 0x3C000000u : 0u);
        }

#pragma unroll
        for (int nt = 0; nt < 4; ++nt) {
            U4 bv;
            bv.u4 = *(const uint4*)&Hw[(16 * nt + c15) * 20 + 4 * Q];
            pacc[nt] = __builtin_amdgcn_mfma_f32_16x16x32_f16(mf.h8, bv.h8, pacc[nt], 0, 0, 0);
        }
        wave_lds_sync();
    }

    if (Q < 2) {
#pragma unroll
        for (int r = 0; r < 4; ++r) {
            const float rc = Q ? rcpc[4 + r] : rcpc[r];
#pragma unroll
            for (int nt = 0; nt < 4; ++nt)
                hb[wave][4 * Q + r][16 * nt + c15] = f16b(pacc[nt][r] * rc);
        }
    }
    wave_lds_sync();

    const int sA = lane & 7;
    half8 afrag[2];
#pragma unroll
    for (int kt = 0; kt < 2; ++kt) {
        U4 cv;
        cv.u4 = *(const uint4*)&hb[wave][sA][kt * 32 + Q * 8];
        afrag[kt] = cv.h8;
    }

    float4v acc[8];
#pragma unroll
    for (int nt = 0; nt < 8; ++nt) {
        U4 f0, f1;
        f0.u4 = *(const uint4*)&w2f[(0 * 8 + nt) * 256 + 4 * lane];
        f1.u4 = *(const uint4*)&w2f[(1 * 8 + nt) * 256 + 4 * lane];
        float4v z = {0.f, 0.f, 0.f, 0.f};
        acc[nt] = __builtin_amdgcn_mfma_f32_16x16x32_f16(afrag[0], f0.h8, z, 0, 0, 0);
        acc[nt] = __builtin_amdgcn_mfma_f32_16x16x32_f16(afrag[1], f1.h8, acc[nt], 0, 0, 0);
    }

    if (Q < 2) {
        float fs[4];
#pragma unroll
        for (int r = 0; r < 4; ++r) fs[r] = (float)((nonempty >> (4 * Q + r)) & 1u);

        const float* b2b = b2 + c15;
        float b2v[8];
#pragma unroll
        for (int nt = 0; nt < 8; ++nt) b2v[nt] = b2b[16 * nt];

        float* obase = out + (size_t)(set0 + 4 * Q) * OUTD + c15;
#pragma unroll
        for (int nt = 0; nt < 8; ++nt) {
#pragma unroll
            for (int r = 0; r < 4; ++r)
                obase[r * OUTD + nt * 16] = fmaf(fs[r], b2v[nt], acc[nt][r]);
        }
    }
}

extern "C" void kernel_launch(void* const* d_in, const int* in_sizes, int n_in,
                              void* d_out, int out_size, void* d_ws, size_t ws_size,
                              hipStream_t stream) {
    const float* player_locs = (const float*)d_in[0];
    const float* actor_locs  = (const float*)d_in[1];
    const float* flags       = (const float*)d_in[2];
    const int*   mask        = (const int*)d_in[3];
    const float* W1          = (const float*)d_in[4];
    const float* b1          = (const float*)d_in[5];
    const float* W2          = (const float*)d_in[6];
    const float* b2          = (const float*)d_in[7];
    float*       out         = (float*)d_out;

    const int B = in_sizes[0] / (PMAX * 2);  // 65536
    const int sets_per_block = WAVES_PER_BLOCK * SETS_PER_WAVE;  // 32
    const int grid = (B + sets_per_block - 1) / sets_per_block;  // 2048

    hipLaunchKernelGGL(set_encoder_kernel, dim3(grid), dim3(256), 0, stream,
                       player_locs, actor_locs, flags, mask, W1, b1, W2, b2, out);
}